// Round 13
// baseline (51584.674 us; speedup 1.0000x reference)
//
#include <hip/hip_runtime.h>
#include <stdint.h>

// SequentialFeedForward: autoregressive 6-layer MLP, L=2048 steps.
// R13: R10 champion + WAVE-AUTONOMOUS stages. Each wave fully owns 8 rows
// (lane l: 8 rows x cols 32l..32l+31), so the 2048-wide dot reduces
// entirely in-wave (merged butterfly -> lane l holds row l&7):
//  - G1/G2: poll -> dot -> emit with NO LDS / NO __syncthreads
//  - G3: same + per-wave W5 partial (256 partials, 64x replicated)
//  - G0: per-wave y-reduce (4 contiguous u64/lane), its barrier dropped;
//    layer-1 keeps R10 structure (1 barrier/step)
// Exchange protocol (tags, 16x replicas, hot polls, N_IDLE sleeps) = R10.

typedef uint32_t u32;
typedef unsigned long long ull;
typedef _Float16 half_t;
typedef _Float16 half2_t __attribute__((ext_vector_type(2)));

#define L_SEQ 2048
#define WIDTH 2048
#define WS    32
#define NAA   21
#define INS   704   // WS*NAA + WS
#define NB    256
#define NREP  16    // h-record replication factor (4 consumers per replica)
#define SLP_IDLE 20 // ~0.53 us per unit
#define N_IDLE   3  // idle sleeps after emit

__device__ __forceinline__ float h2f(u32 b){
  union { unsigned short u; half_t h; } c; c.u = (unsigned short)(b & 0xffffu);
  return (float)c.h;
}
__device__ __forceinline__ u32 f2h(float f){
  union { unsigned short u; half_t h; } c; c.h = (half_t)f;
  return (u32)c.u;
}
__device__ __forceinline__ float fdot2f(u32 a, u32 b, float c){
#if __has_builtin(__builtin_amdgcn_fdot2)
  union { u32 u; half2_t v; } ca, cb; ca.u = a; cb.u = b;
  return __builtin_amdgcn_fdot2(ca.v, cb.v, c, false);
#else
  return c + h2f(a)*h2f(b) + h2f(a>>16)*h2f(b>>16);
#endif
}
__device__ __forceinline__ u32 aload(const u32* p){
  return __hip_atomic_load(const_cast<u32*>(p), __ATOMIC_RELAXED, __HIP_MEMORY_SCOPE_AGENT);
}
__device__ __forceinline__ void astore(u32* p, u32 v){
  __hip_atomic_store(p, v, __ATOMIC_RELAXED, __HIP_MEMORY_SCOPE_AGENT);
}
__device__ __forceinline__ ull aload64(const ull* p){
  return __hip_atomic_load(const_cast<ull*>(p), __ATOMIC_RELAXED, __HIP_MEMORY_SCOPE_AGENT);
}
__device__ __forceinline__ void astore64(ull* p, ull v){
  __hip_atomic_store(p, v, __ATOMIC_RELAXED, __HIP_MEMORY_SCOPE_AGENT);
}

// ---- pre-pass: transpose W0 (for coalesced c0 gather) ----
__global__ void k_wt(const float* __restrict__ W0, float* __restrict__ W0T){
  int tid = blockIdx.x*256 + threadIdx.x;
  if (tid < INS*WIDTH){
    int c = tid >> 11, i = tid & 2047;
    W0T[(size_t)c*WIDTH + i] = W0[(size_t)i*INS + c];
  }
}

// ---- pre-pass: W1 (layer 1, G0) old layout ----
// Wp[r*256+j] uint4: comp q = half2(W1[r][256*(2q)+j], W1[r][256*(2q+1)+j])
__global__ void k_wc0(const float* __restrict__ W1, uint4* __restrict__ Wp){
  int r = blockIdx.x; int j = threadIdx.x;
  const float* row = W1 + (size_t)r*WIDTH;
  u32 o[4];
  #pragma unroll
  for (int q=0;q<4;++q)
    o[q] = f2h(row[256*(2*q)+j]) | (f2h(row[256*(2*q+1)+j]) << 16);
  Wp[(size_t)r*256 + j] = make_uint4(o[0],o[1],o[2],o[3]);
}

// ---- pre-pass: W2..W4 (layers 2-4, G1..G3) wave-autonomous layout ----
// Wp[((1+l3)*2048 + r)*256 + j] uint4 = cols 8j..8j+7 of row r (half2 pairs)
__global__ void k_wc2(const float* __restrict__ B, const float* __restrict__ C,
                      const float* __restrict__ D, uint4* __restrict__ Wp){
  int b = blockIdx.x; int l3 = b >> 11; int r = b & 2047; int j = threadIdx.x;
  const float* S = (l3==0)?B:(l3==1)?C:D;
  const float2* p2 = (const float2*)(S + (size_t)r*WIDTH + 8*j);
  u32 o[4];
  #pragma unroll
  for (int q=0;q<4;++q){
    float2 v = p2[q];
    o[q] = f2h(v.x) | (f2h(v.y) << 16);
  }
  Wp[((size_t)(1+l3)*2048 + r)*256 + j] = make_uint4(o[0],o[1],o[2],o[3]);
}

// ---- pre-pass: c0[t][col] = b0 + one-hot gather; thread j owns cols {256k+j} ----
__global__ void k_c0(const int* __restrict__ x, const float* __restrict__ W0T,
                     const float* __restrict__ b0, uint4* __restrict__ c0p){
  int t = blockIdx.x, j = threadIdx.x;
  __shared__ int cidx[WS];
  if (j < WS){
    int s = t - (WS-1) + j;
    cidx[j] = (s >= 0) ? (NAA*j + x[s]) : -1;
  }
  __syncthreads();
  float acc[8];
  #pragma unroll
  for (int k=0;k<8;++k) acc[k] = b0[256*k + j];
  for (int m=0;m<WS;++m){
    int c = cidx[m];
    if (c >= 0){
      const float* col = W0T + (size_t)c*WIDTH;
      #pragma unroll
      for (int k=0;k<8;++k) acc[k] += col[256*k + j];
    }
  }
  u32 o[4];
  #pragma unroll
  for (int q=0;q<4;++q) o[q] = f2h(acc[2*q]) | (f2h(acc[2*q+1]) << 16);
  c0p[(size_t)t*256 + j] = make_uint4(o[0],o[1],o[2],o[3]);
}

// ---- pre-pass: window weights for G0's idle-window streaming ----
__global__ void k_wy(const float* __restrict__ W0, u32* __restrict__ wyb){
  int b = blockIdx.x; int k = b >> 4, p = b & 15; int j = threadIdx.x;
  int col = 256*k + j;
  float a = W0[(size_t)col*INS + (INS-WS) + 2*p];
  float c = W0[(size_t)col*INS + (INS-WS) + 2*p + 1];
  wyb[(size_t)b*256 + j] = f2h(a) | (f2h(c) << 16);
}

// ---- pre-pass: reset exchange buffers (every launch: replay-safe) ----
__global__ void k_reset(u32* __restrict__ hr, u32* __restrict__ pr){
  int tid = blockIdx.x*256 + threadIdx.x;
  if (tid < 3*NREP*2048) hr[tid] = 0xFFFFFFFFu;   // 3 hop bufs x 16 reps
  if (tid < 64*256*2)    pr[tid] = 0xFFFFFFFFu;   // 64 reps x 256 u64
}

// ---- main persistent dataflow kernel ----
__global__ __launch_bounds__(256, 1) void k_main(
    const float* __restrict__ W0,
    const float* __restrict__ b1, const float* __restrict__ b2,
    const float* __restrict__ b3, const float* __restrict__ b4,
    const float* __restrict__ W5, const float* __restrict__ b5p,
    const uint4* __restrict__ Wp, const uint4* __restrict__ c0p,
    const u32* __restrict__ wyb,
    u32* hrep, ull* prep, float* __restrict__ out)
{
  const int j  = threadIdx.x;
  const int X  = blockIdx.x;
  const int g  = X >> 6;      // stage group 0..3
  const int Xl = X & 63;      // block within group
  const int lw = j & 63;      // lane
  const int w  = j >> 6;      // wave

  __shared__ float red[2][4][32];   // G0 only, double-buffered by t&1
  __shared__ float bias_lds[32];    // G0 only

  // stagger pipeline-fill
  for (int i=0;i<g;++i) __builtin_amdgcn_s_sleep(SLP_IDLE);

  if (g > 0){
    // ======== G1/G2/G3: wave-autonomous stage (no LDS, no barrier) ========
    // wave w owns rows 32*Xl+8w .. +7; lane lw holds cols 32*lw..32*lw+31
    const int rowl = 32*Xl + 8*w + (lw & 7);   // this lane's emit row
    uint4 wreg[32];                             // [rr][q]
    #pragma unroll
    for (int rr=0;rr<8;++rr)
      #pragma unroll
      for (int q=0;q<4;++q)
        wreg[rr*4+q] = Wp[((size_t)g*2048 + 32*Xl + 8*w + rr)*256 + 4*lw + q];
    const float* bp = (g==1)?b2:(g==2)?b3:b4;
    const float bv  = bp[rowl];
    const float w5v = (g==3) ? W5[rowl] : 0.f;

    const ull* b64 = (const ull*)(hrep + ((size_t)(g-1)*NREP + (Xl>>2))*2048)
                     + 16*lw;
    u32* dst = hrep + (size_t)g*NREP*2048;      // used by g=1,2

    u32 hh[16];
    #pragma unroll 1
    for (int t=0; t<L_SEQ; ++t){
      const u32 tag = (u32)t;
      // poll: 16 contiguous u64 (lane's 32 records)
      ull r64[16];
      for(;;){
        #pragma unroll
        for (int k=0;k<16;++k) r64[k] = aload64(b64 + k);
        bool ok = true;
        #pragma unroll
        for (int k=0;k<16;++k)
          ok &= (((u32)r64[k] >> 16) == tag) & (((u32)(r64[k]>>32) >> 16) == tag);
        if (ok) break;
      }
      #pragma unroll
      for (int k=0;k<16;++k)
        hh[k] = ((u32)r64[k] & 0xffffu) | ((u32)(r64[k]>>32) << 16);

      // dot: 8 rows x 32 cols per lane
      float acc[8];
      #pragma unroll
      for (int rr=0;rr<8;++rr){
        float a = 0.f;
        #pragma unroll
        for (int q=0;q<4;++q){
          uint4 W = wreg[rr*4+q];
          a = fdot2f(W.x, hh[4*q+0], a);
          a = fdot2f(W.y, hh[4*q+1], a);
          a = fdot2f(W.z, hh[4*q+2], a);
          a = fdot2f(W.w, hh[4*q+3], a);
        }
        acc[rr] = a;
      }
      // merged in-wave butterfly -> lane lw holds full sum of row (lw&7)
      float m[4];
      #pragma unroll
      for (int i=0;i<4;++i){
        float ta = acc[2*i]   + __shfl_xor(acc[2*i],   1);
        float tb = acc[2*i+1] + __shfl_xor(acc[2*i+1], 1);
        m[i] = (lw & 1) ? tb : ta;
      }
      float n[2];
      #pragma unroll
      for (int i=0;i<2;++i){
        float ta = m[2*i]   + __shfl_xor(m[2*i],   2);
        float tb = m[2*i+1] + __shfl_xor(m[2*i+1], 2);
        n[i] = (lw & 2) ? tb : ta;
      }
      float ta = n[0] + __shfl_xor(n[0], 4);
      float tb = n[1] + __shfl_xor(n[1], 4);
      float tot = (lw & 4) ? tb : ta;
      tot += __shfl_xor(tot, 8);
      tot += __shfl_xor(tot, 16);
      tot += __shfl_xor(tot, 32);

      float s = fmaxf(tot + bv, 0.f);
      if (g < 3){
        u32 rv = (tag << 16) | f2h(s);
        astore(dst + (size_t)(lw>>3)*2048 + rowl, rv);
        astore(dst + (size_t)((lw>>3)+8)*2048 + rowl, rv);
      } else {
        float pp = s * w5v;
        pp += __shfl_xor(pp, 1);
        pp += __shfl_xor(pp, 2);
        pp += __shfl_xor(pp, 4);   // wave partial (identical on all lanes)
        astore64(prep + (size_t)lw*256 + 4*Xl + w,
                 ((ull)tag << 32) | (ull)__float_as_uint(pp));
      }
      for (int i=0;i<N_IDLE;++i) __builtin_amdgcn_s_sleep(SLP_IDLE);
    }
  } else {
    // ======== G0: per-wave y-reduce + h0 window + layer 1 (R10 core) ========
    const int r = j & 31;
    uint4 wreg[32];
    #pragma unroll
    for (int i=0;i<32;++i)
      wreg[i] = Wp[((size_t)32*Xl + i)*256 + j];
    if (j < 32) bias_lds[j] = b1[32*Xl + j];
    float w31v[8];
    #pragma unroll
    for (int k=0;k<8;++k)
      w31v[k] = W0[(size_t)(256*k + j)*INS + (INS-1)];
    const float b5v = b5p[0];
    u32 yqp[16];
    #pragma unroll
    for (int p=0;p<16;++p) yqp[p] = 0u;
    float u_part[8];
    #pragma unroll
    for (int k=0;k<8;++k) u_part[k] = 0.f;
    const ull* yb = prep + (size_t)Xl*256 + 4*lw;   // lane's 4 partials (32B)
    u32* dst = hrep;   // hop buffer 0
    u32 hh[4];

    auto dotsbfly = [&](int buf){
      float c32[32];
      #pragma unroll
      for (int i=0;i<32;++i){
        float a = 0.f;
        a = fdot2f(wreg[i].x, hh[0], a);
        a = fdot2f(wreg[i].y, hh[1], a);
        a = fdot2f(wreg[i].z, hh[2], a);
        a = fdot2f(wreg[i].w, hh[3], a);
        c32[i] = a;
      }
      float c16[16];
      #pragma unroll
      for (int i=0;i<16;++i){
        float v = c32[2*i]   + __shfl_xor(c32[2*i],   1);
        float u = c32[2*i+1] + __shfl_xor(c32[2*i+1], 1);
        c16[i] = (lw & 1) ? u : v;
      }
      float c8[8];
      #pragma unroll
      for (int i=0;i<8;++i){
        float v = c16[2*i]   + __shfl_xor(c16[2*i],   2);
        float u = c16[2*i+1] + __shfl_xor(c16[2*i+1], 2);
        c8[i] = (lw & 2) ? u : v;
      }
      float c4[4];
      #pragma unroll
      for (int i=0;i<4;++i){
        float v = c8[2*i]   + __shfl_xor(c8[2*i],   4);
        float u = c8[2*i+1] + __shfl_xor(c8[2*i+1], 4);
        c4[i] = (lw & 4) ? u : v;
      }
      float c2[2];
      #pragma unroll
      for (int i=0;i<2;++i){
        float v = c4[2*i]   + __shfl_xor(c4[2*i],   8);
        float u = c4[2*i+1] + __shfl_xor(c4[2*i+1], 8);
        c2[i] = (lw & 8) ? u : v;
      }
      float v1 = c2[0] + __shfl_xor(c2[0], 16);
      float u1 = c2[1] + __shfl_xor(c2[1], 16);
      float c1 = (lw & 16) ? u1 : v1;
      float tot = c1 + __shfl_xor(c1, 32);
      if (lw < 32) red[buf][w][lw] = tot;
    };

    #pragma unroll 1
    for (int t=0; t<L_SEQ; ++t){
      const int buf = t & 1;
      uint4 c0v = c0p[(size_t)t*256 + j];
      float y = 0.f;
      if (t > 0){
        const u32 tag = (u32)(t-1);
        ull v0,v1,v2,v3;
        for(;;){
          v0 = aload64(yb+0); v1 = aload64(yb+1);
          v2 = aload64(yb+2); v3 = aload64(yb+3);
          if (((u32)(v0>>32)==tag) & ((u32)(v1>>32)==tag) &
              ((u32)(v2>>32)==tag) & ((u32)(v3>>32)==tag)) break;
        }
        float p = __uint_as_float((u32)v0) + __uint_as_float((u32)v1)
                + __uint_as_float((u32)v2) + __uint_as_float((u32)v3);
        #pragma unroll
        for (int d=1; d<64; d<<=1) p += __shfl_xor(p, d);
        y = fmaxf(p + b5v, 0.f);
        if (X == 0 && j == 0) out[t-1] = y;
        yqp[15] |= (f2h(y) << 16);
      }
      // h0 cols {256k+j} = relu(c0 + u_part + w31*y)
      {
        u32 c0h[4] = { c0v.x, c0v.y, c0v.z, c0v.w };
        float h0v[8];
        #pragma unroll
        for (int q=0;q<4;++q){
          h0v[2*q]   = fmaxf(h2f(c0h[q])       + u_part[2*q]   + w31v[2*q]*y,   0.f);
          h0v[2*q+1] = fmaxf(h2f(c0h[q] >> 16) + u_part[2*q+1] + w31v[2*q+1]*y, 0.f);
        }
        #pragma unroll
        for (int q=0;q<4;++q) hh[q] = f2h(h0v[2*q]) | (f2h(h0v[2*q+1]) << 16);
      }
      dotsbfly(buf);
      __syncthreads();
      float s = fmaxf(red[buf][0][r]+red[buf][1][r]+red[buf][2][r]+red[buf][3][r]
                      + bias_lds[r], 0.f);
      u32 rv = ((u32)t << 16) | f2h(s);
      astore(dst + (size_t)((j>>5)    )*2048 + 32*Xl + r, rv);
      astore(dst + (size_t)((j>>5) + 8)*2048 + 32*Xl + r, rv);
      // off critical path: slide window, precompute u_part(t+1)
      {
        #pragma unroll
        for (int p=0;p<15;++p) yqp[p] = (yqp[p] >> 16) | (yqp[p+1] << 16);
        yqp[15] = (yqp[15] >> 16);
        #pragma unroll
        for (int k=0;k<8;++k){
          float a = 0.f;
          #pragma unroll
          for (int p=0;p<16;++p)
            a = fdot2f(wyb[(size_t)(16*k+p)*256 + j], yqp[p], a);
          u_part[k] = a;
        }
      }
      for (int i=0;i<N_IDLE;++i) __builtin_amdgcn_s_sleep(SLP_IDLE);
    }

    // epilogue: y[L-1]
    if (X == 0){
      const u32 tag = (u32)(L_SEQ-1);
      ull v0,v1,v2,v3;
      for(;;){
        v0 = aload64(yb+0); v1 = aload64(yb+1);
        v2 = aload64(yb+2); v3 = aload64(yb+3);
        if (((u32)(v0>>32)==tag) & ((u32)(v1>>32)==tag) &
            ((u32)(v2>>32)==tag) & ((u32)(v3>>32)==tag)) break;
      }
      float p = __uint_as_float((u32)v0) + __uint_as_float((u32)v1)
              + __uint_as_float((u32)v2) + __uint_as_float((u32)v3);
      #pragma unroll
      for (int d=1; d<64; d<<=1) p += __shfl_xor(p, d);
      if (j == 0) out[L_SEQ-1] = fmaxf(p + b5v, 0.f);
    }
  }
}

extern "C" void kernel_launch(void* const* d_in, const int* in_sizes, int n_in,
                              void* d_out, int out_size, void* d_ws, size_t ws_size,
                              hipStream_t stream) {
  (void)in_sizes; (void)n_in; (void)out_size; (void)ws_size;
  const int*   x  = (const int*)  d_in[0];
  const float* W0 = (const float*)d_in[1];
  const float* b0 = (const float*)d_in[2];
  const float* W1 = (const float*)d_in[3];
  const float* b1 = (const float*)d_in[4];
  const float* W2 = (const float*)d_in[5];
  const float* b2 = (const float*)d_in[6];
  const float* W3 = (const float*)d_in[7];
  const float* b3 = (const float*)d_in[8];
  const float* W4 = (const float*)d_in[9];
  const float* b4 = (const float*)d_in[10];
  const float* W5 = (const float*)d_in[11];
  const float* b5 = (const float*)d_in[12];
  float* out = (float*)d_out;
  char*  ws  = (char*)d_ws;

  // ws layout (16B-aligned). HR/PR live inside W0T's region: W0T is only
  // read by k_c0, which completes (stream-ordered) before k_reset writes.
  constexpr size_t OFF_WP  = 0;                       // 4*2048*256*16 = 33,554,432
  constexpr size_t OFF_C0  = 33554432;                // 2048*256*16   =  8,388,608
  constexpr size_t OFF_W0T = 41943040;                // 704*2048*4    =  5,767,168
  constexpr size_t OFF_HR  = 41943040;                // 3*16*2048*4   =    393,216
  constexpr size_t OFF_PR  = 42336256;                // 64*256*8      =    131,072
  constexpr size_t OFF_WY  = 47710208;                // 128*256*4     =    131,072

  uint4* Wp  = (uint4*)(ws + OFF_WP);
  uint4* c0p = (uint4*)(ws + OFF_C0);
  float* W0T = (float*)(ws + OFF_W0T);
  u32*   hr  = (u32*)  (ws + OFF_HR);
  u32*   pr  = (u32*)  (ws + OFF_PR);
  ull*   prq = (ull*)  (ws + OFF_PR);
  u32*   wyb = (u32*)  (ws + OFF_WY);

  k_wt   <<<5632, 256, 0, stream>>>(W0, W0T);
  k_wc0  <<<2048, 256, 0, stream>>>(W1, Wp);
  k_wc2  <<<6144, 256, 0, stream>>>(W2, W3, W4, Wp);
  k_c0   <<<2048, 256, 0, stream>>>(x, W0T, b0, c0p);
  k_wy   <<<128,  256, 0, stream>>>(W0, wyb);
  k_reset<<<512,  256, 0, stream>>>(hr, pr);
  k_main <<<NB,   256, 0, stream>>>(W0, b1, b2, b3, b4, W5, b5,
                                    Wp, c0p, wyb, hr, prq, out);
}

// Round 14
// 19662.628 us; speedup vs baseline: 2.6235x; 2.6235x over previous
//
#include <hip/hip_runtime.h>
#include <stdint.h>

// SequentialFeedForward: autoregressive 6-layer MLP, L=2048 steps.
// R14 = R10 champion RESTORED VERBATIM (best measured: 19.66 ms).
// Structure: stage-partitioned dataflow (4 groups x 64 blocks, 32 rows/
// block); h exchanged as tagged u32 records (tag16|fp16) replicated 16x
// (one copy per 4-consumer cluster, hot-polled privately); G3 folds W5 and
// emits 64x-replicated tagged u64 partials; G0 reduces y in-register,
// computes h0 from the precomputed one-hot gather + register window dot;
// single barrier/step (red[] double-buffered by t&1).
// Campaign conclusion (R1-R13): per-hop cost is pinned at ~2.2-2.4us under
// every protocol variant tried; denser polling or wider coverage triggers
// a congestion cliff (R9/R13). This is the measured plateau.

typedef uint32_t u32;
typedef unsigned long long ull;
typedef _Float16 half_t;
typedef _Float16 half2_t __attribute__((ext_vector_type(2)));

#define L_SEQ 2048
#define WIDTH 2048
#define WS    32
#define NAA   21
#define INS   704   // WS*NAA + WS
#define NB    256
#define NREP  16    // h-record replication factor (4 consumers per replica)
#define SLP_IDLE 20 // ~0.53 us per unit
#define N_IDLE   3  // idle sleeps after emit

__device__ __forceinline__ float h2f(u32 b){
  union { unsigned short u; half_t h; } c; c.u = (unsigned short)(b & 0xffffu);
  return (float)c.h;
}
__device__ __forceinline__ u32 f2h(float f){
  union { unsigned short u; half_t h; } c; c.h = (half_t)f;
  return (u32)c.u;
}
__device__ __forceinline__ float fdot2f(u32 a, u32 b, float c){
#if __has_builtin(__builtin_amdgcn_fdot2)
  union { u32 u; half2_t v; } ca, cb; ca.u = a; cb.u = b;
  return __builtin_amdgcn_fdot2(ca.v, cb.v, c, false);
#else
  return c + h2f(a)*h2f(b) + h2f(a>>16)*h2f(b>>16);
#endif
}
__device__ __forceinline__ u32 aload(const u32* p){
  return __hip_atomic_load(const_cast<u32*>(p), __ATOMIC_RELAXED, __HIP_MEMORY_SCOPE_AGENT);
}
__device__ __forceinline__ void astore(u32* p, u32 v){
  __hip_atomic_store(p, v, __ATOMIC_RELAXED, __HIP_MEMORY_SCOPE_AGENT);
}
__device__ __forceinline__ ull aload64(const ull* p){
  return __hip_atomic_load(const_cast<ull*>(p), __ATOMIC_RELAXED, __HIP_MEMORY_SCOPE_AGENT);
}
__device__ __forceinline__ void astore64(ull* p, ull v){
  __hip_atomic_store(p, v, __ATOMIC_RELAXED, __HIP_MEMORY_SCOPE_AGENT);
}

// ---- pre-pass: transpose W0 (for coalesced c0 gather) ----
__global__ void k_wt(const float* __restrict__ W0, float* __restrict__ W0T){
  int tid = blockIdx.x*256 + threadIdx.x;
  if (tid < INS*WIDTH){
    int c = tid >> 11, i = tid & 2047;
    W0T[(size_t)c*WIDTH + i] = W0[(size_t)i*INS + c];
  }
}

// ---- pre-pass: W1..W4 fp32 -> fp16 ----
// Wp[(l*2048+r)*256 + j] uint4: comp q = half2(W[r][256*(2q)+j], W[r][256*(2q+1)+j])
__global__ void k_wc(const float* __restrict__ A, const float* __restrict__ B,
                     const float* __restrict__ C, const float* __restrict__ D,
                     uint4* __restrict__ Wp){
  int b = blockIdx.x; int l = b >> 11; int r = b & 2047; int j = threadIdx.x;
  const float* S = (l==0)?A:(l==1)?B:(l==2)?C:D;
  const float* row = S + (size_t)r*WIDTH;
  u32 o[4];
  #pragma unroll
  for (int q=0;q<4;++q)
    o[q] = f2h(row[256*(2*q)+j]) | (f2h(row[256*(2*q+1)+j]) << 16);
  Wp[(size_t)b*256 + j] = make_uint4(o[0],o[1],o[2],o[3]);
}

// ---- pre-pass: c0[t][col] = b0 + one-hot gather; thread j owns cols {256k+j} ----
__global__ void k_c0(const int* __restrict__ x, const float* __restrict__ W0T,
                     const float* __restrict__ b0, uint4* __restrict__ c0p){
  int t = blockIdx.x, j = threadIdx.x;
  __shared__ int cidx[WS];
  if (j < WS){
    int s = t - (WS-1) + j;
    cidx[j] = (s >= 0) ? (NAA*j + x[s]) : -1;
  }
  __syncthreads();
  float acc[8];
  #pragma unroll
  for (int k=0;k<8;++k) acc[k] = b0[256*k + j];
  for (int m=0;m<WS;++m){
    int c = cidx[m];
    if (c >= 0){
      const float* col = W0T + (size_t)c*WIDTH;
      #pragma unroll
      for (int k=0;k<8;++k) acc[k] += col[256*k + j];
    }
  }
  u32 o[4];
  #pragma unroll
  for (int q=0;q<4;++q) o[q] = f2h(acc[2*q]) | (f2h(acc[2*q+1]) << 16);
  c0p[(size_t)t*256 + j] = make_uint4(o[0],o[1],o[2],o[3]);
}

// ---- pre-pass: window weights for G0's idle-window streaming ----
__global__ void k_wy(const float* __restrict__ W0, u32* __restrict__ wyb){
  int b = blockIdx.x; int k = b >> 4, p = b & 15; int j = threadIdx.x;
  int col = 256*k + j;
  float a = W0[(size_t)col*INS + (INS-WS) + 2*p];
  float c = W0[(size_t)col*INS + (INS-WS) + 2*p + 1];
  wyb[(size_t)b*256 + j] = f2h(a) | (f2h(c) << 16);
}

// ---- pre-pass: reset exchange buffers (every launch: replay-safe) ----
__global__ void k_reset(u32* __restrict__ hr, u32* __restrict__ pr){
  int tid = blockIdx.x*256 + threadIdx.x;
  if (tid < 3*NREP*2048) hr[tid] = 0xFFFFFFFFu;
  if (tid < 8192)        pr[tid] = 0xFFFFFFFFu;
}

// ---- main persistent dataflow kernel ----
__global__ __launch_bounds__(256, 1) void k_main(
    const float* __restrict__ W0,
    const float* __restrict__ b1, const float* __restrict__ b2,
    const float* __restrict__ b3, const float* __restrict__ b4,
    const float* __restrict__ W5, const float* __restrict__ b5p,
    const uint4* __restrict__ Wp, const uint4* __restrict__ c0p,
    const u32* __restrict__ wyb,
    u32* hrep, ull* prep, float* __restrict__ out)
{
  const int j  = threadIdx.x;
  const int X  = blockIdx.x;
  const int g  = X >> 6;      // stage group 0..3
  const int Xl = X & 63;      // block within group
  const int lw = j & 63;
  const int w  = j >> 6;
  const int r  = j & 31;

  __shared__ float red[2][4][32];   // double-buffered by t&1
  __shared__ float bias_lds[32];

  // stage weight slice: rows 32*Xl .. 32*Xl+31 of W_{g+1}
  uint4 wreg[32];
  #pragma unroll
  for (int i=0;i<32;++i)
    wreg[i] = Wp[((size_t)g*2048 + 32*Xl + i)*256 + j];

  const float* bp = (g==0)?b1:(g==1)?b2:(g==2)?b3:b4;
  if (j < 32) bias_lds[j] = bp[32*Xl + j];
  float w5r = 0.f;
  if (g == 3) w5r = W5[32*Xl + r];

  u32 hh[4];

  auto dotsbfly = [&](int buf){
    float c32[32];
    #pragma unroll
    for (int i=0;i<32;++i){
      float a = 0.f;
      a = fdot2f(wreg[i].x, hh[0], a);
      a = fdot2f(wreg[i].y, hh[1], a);
      a = fdot2f(wreg[i].z, hh[2], a);
      a = fdot2f(wreg[i].w, hh[3], a);
      c32[i] = a;
    }
    float c16[16];
    #pragma unroll
    for (int i=0;i<16;++i){
      float v = c32[2*i]   + __shfl_xor(c32[2*i],   1);
      float u = c32[2*i+1] + __shfl_xor(c32[2*i+1], 1);
      c16[i] = (lw & 1) ? u : v;
    }
    float c8[8];
    #pragma unroll
    for (int i=0;i<8;++i){
      float v = c16[2*i]   + __shfl_xor(c16[2*i],   2);
      float u = c16[2*i+1] + __shfl_xor(c16[2*i+1], 2);
      c8[i] = (lw & 2) ? u : v;
    }
    float c4[4];
    #pragma unroll
    for (int i=0;i<4;++i){
      float v = c8[2*i]   + __shfl_xor(c8[2*i],   4);
      float u = c8[2*i+1] + __shfl_xor(c8[2*i+1], 4);
      c4[i] = (lw & 4) ? u : v;
    }
    float c2[2];
    #pragma unroll
    for (int i=0;i<2;++i){
      float v = c4[2*i]   + __shfl_xor(c4[2*i],   8);
      float u = c4[2*i+1] + __shfl_xor(c4[2*i+1], 8);
      c2[i] = (lw & 8) ? u : v;
    }
    float v1 = c2[0] + __shfl_xor(c2[0], 16);
    float u1 = c2[1] + __shfl_xor(c2[1], 16);
    float c1 = (lw & 16) ? u1 : v1;
    float tot = c1 + __shfl_xor(c1, 32);
    if (lw < 32) red[buf][w][lw] = tot;
  };

  auto pollrec = [&](const u32* base, u32 tag, u32 (&rec)[8]){
    for(;;){
      #pragma unroll
      for (int k=0;k<8;++k) rec[k] = aload(base + 256*k);
      bool ok = true;
      #pragma unroll
      for (int k=0;k<8;++k) ok &= ((rec[k] >> 16) == tag);
      if (ok) break;
    }
  };

  for (int i=0;i<g;++i) __builtin_amdgcn_s_sleep(SLP_IDLE);

  if (g == 3){
    const u32* base = hrep + ((size_t)2*NREP + (Xl>>2))*2048 + j;
    #pragma unroll 1
    for (int t=0; t<L_SEQ; ++t){
      const int buf = t & 1;
      u32 rec[8];
      pollrec(base, (u32)t, rec);
      #pragma unroll
      for (int q=0;q<4;++q) hh[q] = (rec[2*q] & 0xffffu) | (rec[2*q+1] << 16);
      dotsbfly(buf);
      __syncthreads();
      float s = fmaxf(red[buf][0][r]+red[buf][1][r]+red[buf][2][r]+red[buf][3][r]
                      + bias_lds[r], 0.f);
      float pp = s * w5r;
      pp += __shfl_xor(pp, 1);
      pp += __shfl_xor(pp, 2);
      pp += __shfl_xor(pp, 4);
      pp += __shfl_xor(pp, 8);
      pp += __shfl_xor(pp, 16);
      if (w == 0)
        astore64(prep + (size_t)lw*64 + Xl,
                 ((ull)(u32)t << 32) | (ull)__float_as_uint(pp));
      for (int i=0;i<N_IDLE;++i) __builtin_amdgcn_s_sleep(SLP_IDLE);
    }
  } else if (g > 0){
    const u32* base = hrep + ((size_t)(g-1)*NREP + (Xl>>2))*2048 + j;
    u32* dst = hrep + (size_t)g*NREP*2048;
    #pragma unroll 1
    for (int t=0; t<L_SEQ; ++t){
      const int buf = t & 1;
      u32 rec[8];
      pollrec(base, (u32)t, rec);
      #pragma unroll
      for (int q=0;q<4;++q) hh[q] = (rec[2*q] & 0xffffu) | (rec[2*q+1] << 16);
      dotsbfly(buf);
      __syncthreads();
      float s = fmaxf(red[buf][0][r]+red[buf][1][r]+red[buf][2][r]+red[buf][3][r]
                      + bias_lds[r], 0.f);
      u32 rv = ((u32)t << 16) | f2h(s);
      astore(dst + (size_t)((j>>5)    )*2048 + 32*Xl + r, rv);
      astore(dst + (size_t)((j>>5) + 8)*2048 + 32*Xl + r, rv);
      for (int i=0;i<N_IDLE;++i) __builtin_amdgcn_s_sleep(SLP_IDLE);
    }
  } else {
    float w31v[8];
    #pragma unroll
    for (int k=0;k<8;++k)
      w31v[k] = W0[(size_t)(256*k + j)*INS + (INS-1)];
    const float b5v = b5p[0];
    u32 yqp[16];
    #pragma unroll
    for (int p=0;p<16;++p) yqp[p] = 0u;
    float u_part[8];
    #pragma unroll
    for (int k=0;k<8;++k) u_part[k] = 0.f;
    const ull* yb = prep + (size_t)Xl*64 + lw;
    u32* dst = hrep;

    #pragma unroll 1
    for (int t=0; t<L_SEQ; ++t){
      const int buf = t & 1;
      uint4 c0v = c0p[(size_t)t*256 + j];
      float y = 0.f;
      if (t > 0){
        const u32 tag = (u32)(t-1);
        ull v;
        for(;;){ v = aload64(yb); if ((u32)(v >> 32) == tag) break; }
        float p = __uint_as_float((u32)v);
        #pragma unroll
        for (int d=1; d<64; d<<=1) p += __shfl_xor(p, d);
        y = fmaxf(p + b5v, 0.f);
        if (X == 0 && j == 0) out[t-1] = y;
        yqp[15] |= (f2h(y) << 16);
      }
      {
        u32 c0h[4] = { c0v.x, c0v.y, c0v.z, c0v.w };
        float h0v[8];
        #pragma unroll
        for (int q=0;q<4;++q){
          h0v[2*q]   = fmaxf(h2f(c0h[q])       + u_part[2*q]   + w31v[2*q]*y,   0.f);
          h0v[2*q+1] = fmaxf(h2f(c0h[q] >> 16) + u_part[2*q+1] + w31v[2*q+1]*y, 0.f);
        }
        #pragma unroll
        for (int q=0;q<4;++q) hh[q] = f2h(h0v[2*q]) | (f2h(h0v[2*q+1]) << 16);
      }
      dotsbfly(buf);
      __syncthreads();
      float s = fmaxf(red[buf][0][r]+red[buf][1][r]+red[buf][2][r]+red[buf][3][r]
                      + bias_lds[r], 0.f);
      u32 rv = ((u32)t << 16) | f2h(s);
      astore(dst + (size_t)((j>>5)    )*2048 + 32*Xl + r, rv);
      astore(dst + (size_t)((j>>5) + 8)*2048 + 32*Xl + r, rv);
      {
        #pragma unroll
        for (int p=0;p<15;++p) yqp[p] = (yqp[p] >> 16) | (yqp[p+1] << 16);
        yqp[15] = (yqp[15] >> 16);
        #pragma unroll
        for (int k=0;k<8;++k){
          float a = 0.f;
          #pragma unroll
          for (int p=0;p<16;++p)
            a = fdot2f(wyb[(size_t)(16*k+p)*256 + j], yqp[p], a);
          u_part[k] = a;
        }
      }
      for (int i=0;i<N_IDLE;++i) __builtin_amdgcn_s_sleep(SLP_IDLE);
    }

    if (X == 0 && j < 64){
      const u32 tag = (u32)(L_SEQ-1);
      ull v;
      for(;;){ v = aload64(yb); if ((u32)(v >> 32) == tag) break; }
      float p = __uint_as_float((u32)v);
      #pragma unroll
      for (int d=1; d<64; d<<=1) p += __shfl_xor(p, d);
      if (j == 0) out[L_SEQ-1] = fmaxf(p + b5v, 0.f);
    }
  }
}

extern "C" void kernel_launch(void* const* d_in, const int* in_sizes, int n_in,
                              void* d_out, int out_size, void* d_ws, size_t ws_size,
                              hipStream_t stream) {
  (void)in_sizes; (void)n_in; (void)out_size; (void)ws_size;
  const int*   x  = (const int*)  d_in[0];
  const float* W0 = (const float*)d_in[1];
  const float* b0 = (const float*)d_in[2];
  const float* W1 = (const float*)d_in[3];
  const float* b1 = (const float*)d_in[4];
  const float* W2 = (const float*)d_in[5];
  const float* b2 = (const float*)d_in[6];
  const float* W3 = (const float*)d_in[7];
  const float* b3 = (const float*)d_in[8];
  const float* W4 = (const float*)d_in[9];
  const float* b4 = (const float*)d_in[10];
  const float* W5 = (const float*)d_in[11];
  const float* b5 = (const float*)d_in[12];
  float* out = (float*)d_out;
  char*  ws  = (char*)d_ws;

  // ws layout (16B-aligned). HR/PR live inside W0T's region: W0T is only
  // read by k_c0, which completes (stream-ordered) before k_reset writes.
  constexpr size_t OFF_WP  = 0;                       // 4*2048*256*16 = 33,554,432
  constexpr size_t OFF_C0  = 33554432;                // 2048*256*16   =  8,388,608
  constexpr size_t OFF_W0T = 41943040;                // 704*2048*4    =  5,767,168
  constexpr size_t OFF_HR  = 41943040;                // 3*16*2048*4   =    393,216
  constexpr size_t OFF_PR  = 42336256;                // 64*64*8       =     32,768
  constexpr size_t OFF_WY  = 47710208;                // 128*256*4     =    131,072

  uint4* Wp  = (uint4*)(ws + OFF_WP);
  uint4* c0p = (uint4*)(ws + OFF_C0);
  float* W0T = (float*)(ws + OFF_W0T);
  u32*   hr  = (u32*)  (ws + OFF_HR);
  u32*   pr  = (u32*)  (ws + OFF_PR);
  ull*   prq = (ull*)  (ws + OFF_PR);
  u32*   wyb = (u32*)  (ws + OFF_WY);

  k_wt   <<<5632, 256, 0, stream>>>(W0, W0T);
  k_wc   <<<8192, 256, 0, stream>>>(W1, W2, W3, W4, Wp);
  k_c0   <<<2048, 256, 0, stream>>>(x, W0T, b0, c0p);
  k_wy   <<<128,  256, 0, stream>>>(W0, wyb);
  k_reset<<<384,  256, 0, stream>>>(hr, pr);
  k_main <<<NB,   256, 0, stream>>>(W0, b1, b2, b3, b4, W5, b5,
                                    Wp, c0p, wyb, hr, prq, out);
}